// Round 3
// baseline (1288.826 us; speedup 1.0000x reference)
//
#include <hip/hip_runtime.h>
#include <hip/hip_bf16.h>

#define T_SEQ 2048
#define NH 32
#define HD 128
#define QKV_N 12288
#define V_OFF 8192

typedef __bf16 bf16;
typedef __attribute__((ext_vector_type(8))) __bf16 bf16x8;
typedef __attribute__((ext_vector_type(4))) float f32x4;

// 8-element load -> bf16x8, converting if the source is f32
__device__ inline bf16x8 load8(const bf16* p) { return *(const bf16x8*)p; }
__device__ inline bf16x8 load8(const float* p) {
    f32x4 a = *(const f32x4*)p;
    f32x4 b = *(const f32x4*)(p + 4);
    bf16x8 r;
    r[0] = (bf16)a[0]; r[1] = (bf16)a[1]; r[2] = (bf16)a[2]; r[3] = (bf16)a[3];
    r[4] = (bf16)b[0]; r[5] = (bf16)b[1]; r[6] = (bf16)b[2]; r[7] = (bf16)b[3];
    return r;
}

// ---------------- GEMM: C[M,N] = A[M,K](lda) @ B[N,K]^T (+bias) -----------
#define BM 128
#define BN 128
#define BK 32

template <typename TA, typename TB, typename TO>
__global__ __launch_bounds__(256, 2)
void gemm_bt_bias(const TA* __restrict__ A, int lda,
                  const TB* __restrict__ B,
                  const float* __restrict__ bias,
                  TO* __restrict__ C, int ldc,
                  int M, int N, int K)
{
    __shared__ bf16 sA[BM * BK];
    __shared__ bf16 sB[BN * BK];
    const int tid  = threadIdx.x;
    const int wave = tid >> 6, lane = tid & 63;
    const int quad = lane >> 4, l16 = lane & 15;
    const int wm = wave >> 1, wn = wave & 1;
    const int rowBase = blockIdx.y * BM;
    const int colBase = blockIdx.x * BN;

    // each thread stages 2 chunks (8 bf16 each) for A and for B
    int c0 = wave * 128 + lane;          // chunk ids c0, c0+64
    int rowA0 = c0 >> 2, kgA0 = c0 & 3;
    int rowA1 = (c0 + 64) >> 2, kgA1 = (c0 + 64) & 3;

    f32x4 acc[4][4] = {};

    for (int k0 = 0; k0 < K; k0 += BK) {
        bf16x8 ra0 = load8(A + (size_t)(rowBase + rowA0) * lda + k0 + kgA0 * 8);
        bf16x8 ra1 = load8(A + (size_t)(rowBase + rowA1) * lda + k0 + kgA1 * 8);
        bf16x8 rb0 = load8(B + (size_t)(colBase + rowA0) * K + k0 + kgA0 * 8);
        bf16x8 rb1 = load8(B + (size_t)(colBase + rowA1) * K + k0 + kgA1 * 8);
        __syncthreads();  // previous iteration's LDS reads done
        *(bf16x8*)(sA + rowA0 * BK + kgA0 * 8) = ra0;
        *(bf16x8*)(sA + rowA1 * BK + kgA1 * 8) = ra1;
        *(bf16x8*)(sB + rowA0 * BK + kgA0 * 8) = rb0;
        *(bf16x8*)(sB + rowA1 * BK + kgA1 * 8) = rb1;
        __syncthreads();

        bf16x8 af[4], bfr[4];
        for (int mi = 0; mi < 4; ++mi)
            af[mi] = *(const bf16x8*)(sA + (wm * 64 + mi * 16 + l16) * BK + quad * 8);
        for (int ni = 0; ni < 4; ++ni)
            bfr[ni] = *(const bf16x8*)(sB + (wn * 64 + ni * 16 + l16) * BK + quad * 8);
        for (int mi = 0; mi < 4; ++mi)
            for (int ni = 0; ni < 4; ++ni)
                acc[mi][ni] = __builtin_amdgcn_mfma_f32_16x16x32_bf16(
                    af[mi], bfr[ni], acc[mi][ni], 0, 0, 0);
    }

    for (int ni = 0; ni < 4; ++ni) {
        int col = colBase + wn * 64 + ni * 16 + l16;
        float bv = bias ? bias[col] : 0.0f;
        for (int mi = 0; mi < 4; ++mi) {
            int row0 = rowBase + wm * 64 + mi * 16 + quad * 4;
            for (int r = 0; r < 4; ++r)
                C[(size_t)(row0 + r) * ldc + col] = (TO)(acc[mi][ni][r] + bv);
        }
    }
}

// ---------------- RMSNorm (over full 4096) + RoPE, IN PLACE ----------------
__global__ __launch_bounds__(256)
void rmsnorm_rope(bf16* __restrict__ qkv, const float* __restrict__ qw,
                  const float* __restrict__ kw, const int* __restrict__ pos)
{
    const int t   = blockIdx.x;
    const int sel = blockIdx.y;  // 0=q, 1=k
    bf16* x = qkv + (size_t)t * QKV_N + sel * 4096;
    const float* w = sel ? kw : qw;
    const int tid = threadIdx.x;

    float ss = 0.f;
    {
        int i0 = tid * 16;
        bf16x8 a = *(const bf16x8*)(x + i0);
        bf16x8 b = *(const bf16x8*)(x + i0 + 8);
        for (int j = 0; j < 8; ++j) { float fa = (float)a[j]; ss += fa * fa; }
        for (int j = 0; j < 8; ++j) { float fb = (float)b[j]; ss += fb * fb; }
    }
    for (int off = 1; off < 64; off <<= 1) ss += __shfl_xor(ss, off, 64);
    __shared__ float red[4];
    if ((tid & 63) == 0) red[tid >> 6] = ss;
    __syncthreads();
    float tot = red[0] + red[1] + red[2] + red[3];
    float rstd = rsqrtf(tot * (1.0f / 4096.0f) + 1e-5f);

    float fp = (float)pos[t];
    for (int i = tid; i < 2048; i += 256) {
        int h = i >> 6;
        int d = i & 63;
        int base = h * 128 + d;
        float x1 = (float)x[base]      * rstd * w[base];
        float x2 = (float)x[base + 64] * rstd * w[base + 64];
        float ang = fp * exp2f(-(float)d * 0.31143075889569023f);
        float s, c;
        sincosf(ang, &s, &c);
        x[base]      = (bf16)(x1 * c - x2 * s);
        x[base + 64] = (bf16)(x2 * c + x1 * s);
    }
}

// ---------------- V transpose: Vt[h*128+d][t] = qkv[t][V_OFF + h*128 + d] ---
__global__ __launch_bounds__(256)
void v_transpose(const bf16* __restrict__ qkv, bf16* __restrict__ vt)
{
    __shared__ bf16 tile[64][65];
    int t0 = blockIdx.x * 64, d0 = blockIdx.y * 64, h = blockIdx.z;
    int x = threadIdx.x & 63, y4 = threadIdx.x >> 6;
    for (int yy = y4; yy < 64; yy += 4)
        tile[yy][x] = qkv[(size_t)(t0 + yy) * QKV_N + V_OFF + h * HD + d0 + x];
    __syncthreads();
    for (int yy = y4; yy < 64; yy += 4)
        vt[(size_t)(h * HD + d0 + yy) * T_SEQ + t0 + x] = tile[x][yy];
}

// ---------------- Flash attention (causal), wave per 16-row Q tile ---------
// q = qkv cols [0,4096), k = qkv cols [4096,8192); writes o into cols [8192,..)
__global__ __launch_bounds__(256, 2)
void flash_attn(bf16* qkv, const bf16* vt)
{
    __shared__ bf16 pbuf[4][16 * 32];
    const int tid  = threadIdx.x;
    const int wave = tid >> 6, lane = tid & 63;
    const int quad = lane >> 4, l16 = lane & 15;
    const int h  = blockIdx.y;
    const int q0 = (blockIdx.x * 4 + wave) * 16;

    bf16x8 qf[4];
    const bf16* qrow = qkv + (size_t)(q0 + l16) * QKV_N + h * HD;
    for (int c = 0; c < 4; ++c)
        qf[c] = *(const bf16x8*)(qrow + c * 32 + quad * 8);

    f32x4 oacc[8] = {};
    float m2[4], l[4];
    for (int r = 0; r < 4; ++r) { m2[r] = -1e30f; l[r] = 0.f; }

    const float sc = 0.08838834764831845f * 1.4426950408889634f;  // scale*log2e
    bf16* pb = pbuf[wave];
    const int rowa = q0 + quad * 4;

    for (int kb = 0; kb <= q0 + 15; kb += 32) {
        f32x4 s[2] = {};
        for (int st = 0; st < 2; ++st) {
            const bf16* krow = qkv + (size_t)(kb + st * 16 + l16) * QKV_N + 4096 + h * HD;
            for (int c = 0; c < 4; ++c) {
                bf16x8 kf = *(const bf16x8*)(krow + c * 32 + quad * 8);
                s[st] = __builtin_amdgcn_mfma_f32_16x16x32_bf16(qf[c], kf, s[st], 0, 0, 0);
            }
        }
        for (int st = 0; st < 2; ++st) {
            int col = kb + st * 16 + l16;
            for (int r = 0; r < 4; ++r) {
                float v = s[st][r] * sc;
                s[st][r] = (col <= rowa + r) ? v : -1e30f;
            }
        }
        float alpha[4];
        for (int r = 0; r < 4; ++r) {
            float mx = fmaxf(s[0][r], s[1][r]);
            for (int off = 1; off < 16; off <<= 1)
                mx = fmaxf(mx, __shfl_xor(mx, off, 64));
            float mnew = fmaxf(m2[r], mx);
            alpha[r] = exp2f(m2[r] - mnew);
            float p0 = exp2f(s[0][r] - mnew);
            float p1 = exp2f(s[1][r] - mnew);
            s[0][r] = p0; s[1][r] = p1;
            float ps = p0 + p1;
            for (int off = 1; off < 16; off <<= 1)
                ps += __shfl_xor(ps, off, 64);
            l[r] = l[r] * alpha[r] + ps;
            m2[r] = mnew;
        }
        for (int c = 0; c < 8; ++c)
            for (int r = 0; r < 4; ++r)
                oacc[c][r] *= alpha[r];
        for (int st = 0; st < 2; ++st)
            for (int r = 0; r < 4; ++r)
                pb[(quad * 4 + r) * 32 + st * 16 + l16] = (bf16)s[st][r];
        __builtin_amdgcn_s_waitcnt(0xC07F);  // lgkmcnt(0): DS writes visible
        bf16x8 pf = *(const bf16x8*)(pb + l16 * 32 + quad * 8);
        const bf16* vtb = vt + (size_t)h * HD * T_SEQ + kb + quad * 8;
        for (int c = 0; c < 8; ++c) {
            bf16x8 vf = *(const bf16x8*)(vtb + (size_t)(c * 16 + l16) * T_SEQ);
            oacc[c] = __builtin_amdgcn_mfma_f32_16x16x32_bf16(pf, vf, oacc[c], 0, 0, 0);
        }
    }

    for (int r = 0; r < 4; ++r) {
        float inv = 1.0f / l[r];
        int t = q0 + quad * 4 + r;
        for (int c = 0; c < 8; ++c)
            qkv[(size_t)t * QKV_N + V_OFF + h * HD + c * 16 + l16] =
                (bf16)(oacc[c][r] * inv);
    }
}

extern "C" void kernel_launch(void* const* d_in, const int* in_sizes, int n_in,
                              void* d_out, int out_size, void* d_ws, size_t ws_size,
                              hipStream_t stream)
{
    const float* hidden   = (const float*)d_in[0];
    const int*   pos      = (const int*)d_in[1];
    const float* w_qkv    = (const float*)d_in[2];
    const float* b_qkv    = (const float*)d_in[3];
    const float* q_norm_w = (const float*)d_in[4];
    const float* k_norm_w = (const float*)d_in[5];
    const float* w_o      = (const float*)d_in[6];
    float* out = (float*)d_out;

    bf16* qkv = (bf16*)d_ws;                     // [2048][12288]
    bf16* vt  = qkv + (size_t)T_SEQ * QKV_N;     // [4096][2048]
    // total ws use: (2048*12288 + 4096*2048)*2 B = 67.1 MB

    gemm_bt_bias<float, float, bf16><<<dim3(QKV_N / BN, T_SEQ / BM), 256, 0, stream>>>(
        hidden, 4096, w_qkv, b_qkv, qkv, QKV_N, T_SEQ, QKV_N, 4096);
    rmsnorm_rope<<<dim3(T_SEQ, 2), 256, 0, stream>>>(qkv, q_norm_w, k_norm_w, pos);
    v_transpose<<<dim3(T_SEQ / 64, 2, NH), 256, 0, stream>>>(qkv, vt);
    flash_attn<<<dim3(T_SEQ / 64, NH), 256, 0, stream>>>(qkv, vt);
    gemm_bt_bias<bf16, float, float><<<dim3(4096 / BN, T_SEQ / BM), 256, 0, stream>>>(
        qkv + V_OFF, QKV_N, w_o, nullptr, out, 4096, T_SEQ, 4096, 4096);
}

// Round 4
// 1041.048 us; speedup vs baseline: 1.2380x; 1.2380x over previous
//
#include <hip/hip_runtime.h>
#include <hip/hip_bf16.h>

#define T_SEQ 2048
#define NH 32
#define HD 128
#define QKV_N 12288
#define V_OFF 8192

typedef __bf16 bf16;
typedef __attribute__((ext_vector_type(8))) __bf16 bf16x8;
typedef __attribute__((ext_vector_type(4))) float f32x4;

// 8-element load -> bf16x8, converting if the source is f32
__device__ inline bf16x8 load8(const bf16* p) { return *(const bf16x8*)p; }
__device__ inline bf16x8 load8(const float* p) {
    f32x4 a = *(const f32x4*)p;
    f32x4 b = *(const f32x4*)(p + 4);
    bf16x8 r;
    r[0] = (bf16)a[0]; r[1] = (bf16)a[1]; r[2] = (bf16)a[2]; r[3] = (bf16)a[3];
    r[4] = (bf16)b[0]; r[5] = (bf16)b[1]; r[6] = (bf16)b[2]; r[7] = (bf16)b[3];
    return r;
}

// ---------------- GEMM: C[M,N] = A[M,K](lda) @ B[N,K]^T (+bias) -----------
// blockIdx.x = row tile (fast dim) so consecutive blocks share the B-strip.
#define BM 128
#define BN 128
#define BK 32

template <typename TA, typename TB, typename TO>
__global__ __launch_bounds__(256, 2)
void gemm_bt_bias(const TA* __restrict__ A, int lda,
                  const TB* __restrict__ B,
                  const float* __restrict__ bias,
                  TO* __restrict__ C, int ldc,
                  int M, int N, int K)
{
    __shared__ bf16 sA[BM * BK];
    __shared__ bf16 sB[BN * BK];
    const int tid  = threadIdx.x;
    const int wave = tid >> 6, lane = tid & 63;
    const int quad = lane >> 4, l16 = lane & 15;
    const int wm = wave >> 1, wn = wave & 1;
    const int rowBase = blockIdx.x * BM;   // x fastest -> B-strip reuse
    const int colBase = blockIdx.y * BN;

    int c0 = wave * 128 + lane;          // chunk ids c0, c0+64
    int rowA0 = c0 >> 2, kgA0 = c0 & 3;
    int rowA1 = (c0 + 64) >> 2, kgA1 = (c0 + 64) & 3;

    f32x4 acc[4][4] = {};

    for (int k0 = 0; k0 < K; k0 += BK) {
        bf16x8 ra0 = load8(A + (size_t)(rowBase + rowA0) * lda + k0 + kgA0 * 8);
        bf16x8 ra1 = load8(A + (size_t)(rowBase + rowA1) * lda + k0 + kgA1 * 8);
        bf16x8 rb0 = load8(B + (size_t)(colBase + rowA0) * K + k0 + kgA0 * 8);
        bf16x8 rb1 = load8(B + (size_t)(colBase + rowA1) * K + k0 + kgA1 * 8);
        __syncthreads();
        *(bf16x8*)(sA + rowA0 * BK + kgA0 * 8) = ra0;
        *(bf16x8*)(sA + rowA1 * BK + kgA1 * 8) = ra1;
        *(bf16x8*)(sB + rowA0 * BK + kgA0 * 8) = rb0;
        *(bf16x8*)(sB + rowA1 * BK + kgA1 * 8) = rb1;
        __syncthreads();

        bf16x8 af[4], bfr[4];
        for (int mi = 0; mi < 4; ++mi)
            af[mi] = *(const bf16x8*)(sA + (wm * 64 + mi * 16 + l16) * BK + quad * 8);
        for (int ni = 0; ni < 4; ++ni)
            bfr[ni] = *(const bf16x8*)(sB + (wn * 64 + ni * 16 + l16) * BK + quad * 8);
        for (int mi = 0; mi < 4; ++mi)
            for (int ni = 0; ni < 4; ++ni)
                acc[mi][ni] = __builtin_amdgcn_mfma_f32_16x16x32_bf16(
                    af[mi], bfr[ni], acc[mi][ni], 0, 0, 0);
    }

    for (int ni = 0; ni < 4; ++ni) {
        int col = colBase + wn * 64 + ni * 16 + l16;
        float bv = bias ? bias[col] : 0.0f;
        for (int mi = 0; mi < 4; ++mi) {
            int row0 = rowBase + wm * 64 + mi * 16 + quad * 4;
            for (int r = 0; r < 4; ++r)
                C[(size_t)(row0 + r) * ldc + col] = (TO)(acc[mi][ni][r] + bv);
        }
    }
}

// ---------------- RMSNorm (over full 4096) + RoPE, IN PLACE ----------------
__global__ __launch_bounds__(256)
void rmsnorm_rope(bf16* __restrict__ qkv, const float* __restrict__ qw,
                  const float* __restrict__ kw, const int* __restrict__ pos)
{
    const int t   = blockIdx.x;
    const int sel = blockIdx.y;  // 0=q, 1=k
    bf16* x = qkv + (size_t)t * QKV_N + sel * 4096;
    const float* w = sel ? kw : qw;
    const int tid = threadIdx.x;

    float ss = 0.f;
    {
        int i0 = tid * 16;
        bf16x8 a = *(const bf16x8*)(x + i0);
        bf16x8 b = *(const bf16x8*)(x + i0 + 8);
        for (int j = 0; j < 8; ++j) { float fa = (float)a[j]; ss += fa * fa; }
        for (int j = 0; j < 8; ++j) { float fb = (float)b[j]; ss += fb * fb; }
    }
    for (int off = 1; off < 64; off <<= 1) ss += __shfl_xor(ss, off, 64);
    __shared__ float red[4];
    if ((tid & 63) == 0) red[tid >> 6] = ss;
    __syncthreads();
    float tot = red[0] + red[1] + red[2] + red[3];
    float rstd = rsqrtf(tot * (1.0f / 4096.0f) + 1e-5f);

    float fp = (float)pos[t];
    for (int i = tid; i < 2048; i += 256) {
        int h = i >> 6;
        int d = i & 63;
        int base = h * 128 + d;
        float x1 = (float)x[base]      * rstd * w[base];
        float x2 = (float)x[base + 64] * rstd * w[base + 64];
        float ang = fp * exp2f(-(float)d * 0.31143075889569023f);
        float s, c;
        sincosf(ang, &s, &c);
        x[base]      = (bf16)(x1 * c - x2 * s);
        x[base + 64] = (bf16)(x2 * c + x1 * s);
    }
}

// ---------------- V transpose: Vt[h*128+d][t] = qkv[t][V_OFF + h*128 + d] ---
__global__ __launch_bounds__(256)
void v_transpose(const bf16* __restrict__ qkv, bf16* __restrict__ vt)
{
    __shared__ bf16 tile[64][65];
    int t0 = blockIdx.x * 64, d0 = blockIdx.y * 64, h = blockIdx.z;
    int x = threadIdx.x & 63, y4 = threadIdx.x >> 6;
    for (int yy = y4; yy < 64; yy += 4)
        tile[yy][x] = qkv[(size_t)(t0 + yy) * QKV_N + V_OFF + h * HD + d0 + x];
    __syncthreads();
    for (int yy = y4; yy < 64; yy += 4)
        vt[(size_t)(h * HD + d0 + yy) * T_SEQ + t0 + x] = tile[x][yy];
}

// ---------------- Flash attention (causal) ---------------------------------
// Block: 4 waves = 64 Q rows of head h. K/V tiles (64 cols) staged in LDS,
// shared by all 4 waves. q/k read from qkv; O written into V's columns.
#define SKP 136   // sK row stride (128 + 8 pad)
#define SVP 72    // sV row stride (64 + 8 pad)
#define PBP 72    // pbuf row stride

__global__ __launch_bounds__(256, 2)
void flash_attn(bf16* qkv, const bf16* vt)
{
    __shared__ bf16 sK[64 * SKP];
    __shared__ bf16 sV[128 * SVP];
    __shared__ bf16 pbuf[4 * 16 * PBP];

    const int tid  = threadIdx.x;
    const int wave = tid >> 6, lane = tid & 63;
    const int quad = lane >> 4, l16 = lane & 15;
    const int h    = blockIdx.y;
    const int blk  = blockIdx.x;
    const int q0w  = blk * 64 + wave * 16;

    bf16x8 qf[4];
    {
        const bf16* qrow = qkv + (size_t)(q0w + l16) * QKV_N + h * HD;
        for (int c = 0; c < 4; ++c)
            qf[c] = *(const bf16x8*)(qrow + c * 32 + quad * 8);
    }

    f32x4 oacc[8] = {};
    float m2[4], l[4];
    for (int r = 0; r < 4; ++r) { m2[r] = -1e30f; l[r] = 0.f; }

    const float sc = 0.08838834764831845f * 1.4426950408889634f;  // scale*log2e
    bf16* pb = pbuf + wave * 16 * PBP;
    const int rowa = q0w + quad * 4;
    const int kend = blk * 64;

    for (int kb = 0; kb <= kend; kb += 64) {
        __syncthreads();  // all waves done with previous sK/sV
        // stage K tile: rows kb..kb+63, 128 cols each (16 chunks of 16B/row)
        for (int j = 0; j < 4; ++j) {
            int c = tid + j * 256;          // 0..1023
            int r = c >> 4, off = (c & 15) * 8;
            bf16x8 v = *(const bf16x8*)(qkv + (size_t)(kb + r) * QKV_N + 4096 + h * HD + off);
            *(bf16x8*)(sK + r * SKP + off) = v;
        }
        // stage V^T tile: 128 d-rows, 64 t-cols each (8 chunks of 16B/row)
        for (int j = 0; j < 4; ++j) {
            int c = tid + j * 256;
            int d = c >> 3, off = (c & 7) * 8;
            bf16x8 v = *(const bf16x8*)(vt + (size_t)(h * HD + d) * T_SEQ + kb + off);
            *(bf16x8*)(sV + d * SVP + off) = v;
        }
        __syncthreads();

        const bool diag = (kb == kend);
        const int stmax = diag ? (wave + 1) : 4;

        f32x4 s[4] = {};
        for (int st = 0; st < 4; ++st) {
            if (st >= stmax) break;
            const bf16* kbase = sK + (st * 16 + l16) * SKP + quad * 8;
            for (int c = 0; c < 4; ++c) {
                bf16x8 kf = *(const bf16x8*)(kbase + c * 32);
                s[st] = __builtin_amdgcn_mfma_f32_16x16x32_bf16(qf[c], kf, s[st], 0, 0, 0);
            }
        }
        // scale + causal mask (cheap predication; exact in all cases)
        for (int st = 0; st < 4; ++st) {
            int col = kb + st * 16 + l16;
            for (int r = 0; r < 4; ++r) {
                float v = s[st][r] * sc;
                s[st][r] = (col <= rowa + r) ? v : -1e30f;
            }
        }
        // online softmax over 64 columns
        float alpha[4];
        for (int r = 0; r < 4; ++r) {
            float mx = fmaxf(fmaxf(s[0][r], s[1][r]), fmaxf(s[2][r], s[3][r]));
            for (int off = 1; off < 16; off <<= 1)
                mx = fmaxf(mx, __shfl_xor(mx, off, 64));
            float mnew = fmaxf(m2[r], mx);
            alpha[r] = exp2f(m2[r] - mnew);
            float ps = 0.f;
            for (int st = 0; st < 4; ++st) {
                float p = exp2f(s[st][r] - mnew);
                s[st][r] = p;
                ps += p;
            }
            for (int off = 1; off < 16; off <<= 1)
                ps += __shfl_xor(ps, off, 64);
            l[r] = l[r] * alpha[r] + ps;
            m2[r] = mnew;
        }
        for (int c = 0; c < 8; ++c)
            for (int r = 0; r < 4; ++r)
                oacc[c][r] *= alpha[r];
        // P -> LDS (C-layout) -> A-layout fragments
        for (int st = 0; st < 4; ++st)
            for (int r = 0; r < 4; ++r)
                pb[(quad * 4 + r) * PBP + st * 16 + l16] = (bf16)s[st][r];
        __builtin_amdgcn_s_waitcnt(0xC07F);  // lgkmcnt(0): DS writes visible
        for (int ph = 0; ph < 2; ++ph) {
            bf16x8 pf = *(const bf16x8*)(pb + l16 * PBP + ph * 32 + quad * 8);
            for (int c = 0; c < 8; ++c) {
                bf16x8 vf = *(const bf16x8*)(sV + (c * 16 + l16) * SVP + ph * 32 + quad * 8);
                oacc[c] = __builtin_amdgcn_mfma_f32_16x16x32_bf16(pf, vf, oacc[c], 0, 0, 0);
            }
        }
    }

    for (int r = 0; r < 4; ++r) {
        float inv = 1.0f / l[r];
        int t = q0w + quad * 4 + r;
        for (int c = 0; c < 8; ++c)
            qkv[(size_t)t * QKV_N + V_OFF + h * HD + c * 16 + l16] =
                (bf16)(oacc[c][r] * inv);
    }
}

extern "C" void kernel_launch(void* const* d_in, const int* in_sizes, int n_in,
                              void* d_out, int out_size, void* d_ws, size_t ws_size,
                              hipStream_t stream)
{
    const float* hidden   = (const float*)d_in[0];
    const int*   pos      = (const int*)d_in[1];
    const float* w_qkv    = (const float*)d_in[2];
    const float* b_qkv    = (const float*)d_in[3];
    const float* q_norm_w = (const float*)d_in[4];
    const float* k_norm_w = (const float*)d_in[5];
    const float* w_o      = (const float*)d_in[6];
    float* out = (float*)d_out;

    bf16* qkv = (bf16*)d_ws;                     // [2048][12288]
    bf16* vt  = qkv + (size_t)T_SEQ * QKV_N;     // [4096][2048]
    // total ws use: (2048*12288 + 4096*2048)*2 B = 67.1 MB

    gemm_bt_bias<float, float, bf16><<<dim3(T_SEQ / BM, QKV_N / BN), 256, 0, stream>>>(
        hidden, 4096, w_qkv, b_qkv, qkv, QKV_N, T_SEQ, QKV_N, 4096);
    rmsnorm_rope<<<dim3(T_SEQ, 2), 256, 0, stream>>>(qkv, q_norm_w, k_norm_w, pos);
    v_transpose<<<dim3(T_SEQ / 64, 2, NH), 256, 0, stream>>>(qkv, vt);
    flash_attn<<<dim3(T_SEQ / 64, NH), 256, 0, stream>>>(qkv, vt);
    gemm_bt_bias<bf16, float, float><<<dim3(T_SEQ / BM, 4096 / BN), 256, 0, stream>>>(
        qkv + V_OFF, QKV_N, w_o, nullptr, out, 4096, T_SEQ, 4096, 4096);
}

// Round 5
// 960.409 us; speedup vs baseline: 1.3420x; 1.0840x over previous
//
#include <hip/hip_runtime.h>
#include <hip/hip_bf16.h>

#define T_SEQ 2048
#define NH 32
#define HD 128
#define QKV_N 12288
#define V_OFF 8192

typedef __bf16 bf16;
typedef __attribute__((ext_vector_type(8))) __bf16 bf16x8;
typedef __attribute__((ext_vector_type(4))) float f32x4;

#define GLDS16(g, l)                                                        \
  __builtin_amdgcn_global_load_lds(                                         \
      (const __attribute__((address_space(1))) void*)(g),                   \
      (__attribute__((address_space(3))) void*)(l), 16, 0, 0)

// 8-element load -> bf16x8, converting if the source is f32
__device__ inline bf16x8 load8(const bf16* p) { return *(const bf16x8*)p; }
__device__ inline bf16x8 load8(const float* p) {
    f32x4 a = *(const f32x4*)p;
    f32x4 b = *(const f32x4*)(p + 4);
    bf16x8 r;
    r[0] = (bf16)a[0]; r[1] = (bf16)a[1]; r[2] = (bf16)a[2]; r[3] = (bf16)a[3];
    r[4] = (bf16)b[0]; r[5] = (bf16)b[1]; r[6] = (bf16)b[2]; r[7] = (bf16)b[3];
    return r;
}

// ---------------- f32 -> bf16 bulk convert ---------------------------------
__global__ __launch_bounds__(256)
void f32_to_bf16(const float* __restrict__ in, bf16* __restrict__ out, int n8)
{
    for (int i = blockIdx.x * 256 + threadIdx.x; i < n8; i += gridDim.x * 256)
        *(bf16x8*)(out + (size_t)i * 8) = load8(in + (size_t)i * 8);
}

#define BM 128
#define BN 128
#define BK 32

// ---------------- fast GEMM: bf16 A,B; GLDS staging; XCD swizzle -----------
// C[M,N] = A[M,K](lda) @ B[N,K]^T (+bias). 1-D grid, 8*mTiles*colPerXcd blocks.
template <typename TO>
__global__ __launch_bounds__(256, 2)
void gemm_bt_glds(const bf16* __restrict__ A, int lda,
                  const bf16* __restrict__ B,
                  const float* __restrict__ bias,
                  TO* __restrict__ C, int ldc,
                  int mTiles, int colPerXcd, int K)
{
    __shared__ bf16 sA[BM * BK];
    __shared__ bf16 sB[BN * BK];
    const int tid  = threadIdx.x;
    const int wave = tid >> 6, lane = tid & 63;
    const int quad = lane >> 4, l16 = lane & 15;
    const int wm = wave >> 1, wn = wave & 1;

    // XCD-aware mapping: block b -> xcd b&7 (round-robin heuristic);
    // within an XCD iterate row tiles fastest so the B strip stays in its L2.
    int b = blockIdx.x;
    int xcd = b & 7, i = b >> 3;
    const int rowBase = (i % mTiles) * BM;
    const int colBase = (xcd * colPerXcd + i / mTiles) * BN;

    f32x4 acc[4][4] = {};

    for (int k0 = 0; k0 < K; k0 += BK) {
        __syncthreads();
        for (int r = 0; r < 2; ++r) {
            int cb = wave * 128 + r * 64;   // wave-uniform chunk base
            int c  = cb + lane;
            int row = c >> 2, kg = c & 3;
            GLDS16(A + (size_t)(rowBase + row) * lda + k0 + kg * 8, sA + cb * 8);
            GLDS16(B + (size_t)(colBase + row) * K + k0 + kg * 8, sB + cb * 8);
        }
        __syncthreads();

        bf16x8 af[4], bfr[4];
        for (int mi = 0; mi < 4; ++mi)
            af[mi] = *(const bf16x8*)(sA + (wm * 64 + mi * 16 + l16) * BK + quad * 8);
        for (int ni = 0; ni < 4; ++ni)
            bfr[ni] = *(const bf16x8*)(sB + (wn * 64 + ni * 16 + l16) * BK + quad * 8);
        for (int mi = 0; mi < 4; ++mi)
            for (int ni = 0; ni < 4; ++ni)
                acc[mi][ni] = __builtin_amdgcn_mfma_f32_16x16x32_bf16(
                    af[mi], bfr[ni], acc[mi][ni], 0, 0, 0);
    }

    for (int ni = 0; ni < 4; ++ni) {
        int col = colBase + wn * 64 + ni * 16 + l16;
        float bv = bias ? bias[col] : 0.0f;
        for (int mi = 0; mi < 4; ++mi) {
            int row0 = rowBase + wm * 64 + mi * 16 + quad * 4;
            for (int r = 0; r < 4; ++r)
                C[(size_t)(row0 + r) * ldc + col] = (TO)(acc[mi][ni][r] + bv);
        }
    }
}

// ---------------- fallback GEMM (mixed dtype, register staging) ------------
template <typename TA, typename TB, typename TO>
__global__ __launch_bounds__(256, 2)
void gemm_bt_bias(const TA* __restrict__ A, int lda,
                  const TB* __restrict__ B,
                  const float* __restrict__ bias,
                  TO* __restrict__ C, int ldc,
                  int M, int N, int K)
{
    __shared__ bf16 sA[BM * BK];
    __shared__ bf16 sB[BN * BK];
    const int tid  = threadIdx.x;
    const int wave = tid >> 6, lane = tid & 63;
    const int quad = lane >> 4, l16 = lane & 15;
    const int wm = wave >> 1, wn = wave & 1;
    const int rowBase = blockIdx.x * BM;
    const int colBase = blockIdx.y * BN;

    int c0 = wave * 128 + lane;
    int rowA0 = c0 >> 2, kgA0 = c0 & 3;
    int rowA1 = (c0 + 64) >> 2, kgA1 = (c0 + 64) & 3;

    f32x4 acc[4][4] = {};

    for (int k0 = 0; k0 < K; k0 += BK) {
        bf16x8 ra0 = load8(A + (size_t)(rowBase + rowA0) * lda + k0 + kgA0 * 8);
        bf16x8 ra1 = load8(A + (size_t)(rowBase + rowA1) * lda + k0 + kgA1 * 8);
        bf16x8 rb0 = load8(B + (size_t)(colBase + rowA0) * K + k0 + kgA0 * 8);
        bf16x8 rb1 = load8(B + (size_t)(colBase + rowA1) * K + k0 + kgA1 * 8);
        __syncthreads();
        *(bf16x8*)(sA + rowA0 * BK + kgA0 * 8) = ra0;
        *(bf16x8*)(sA + rowA1 * BK + kgA1 * 8) = ra1;
        *(bf16x8*)(sB + rowA0 * BK + kgA0 * 8) = rb0;
        *(bf16x8*)(sB + rowA1 * BK + kgA1 * 8) = rb1;
        __syncthreads();

        bf16x8 af[4], bfr[4];
        for (int mi = 0; mi < 4; ++mi)
            af[mi] = *(const bf16x8*)(sA + (wm * 64 + mi * 16 + l16) * BK + quad * 8);
        for (int ni = 0; ni < 4; ++ni)
            bfr[ni] = *(const bf16x8*)(sB + (wn * 64 + ni * 16 + l16) * BK + quad * 8);
        for (int mi = 0; mi < 4; ++mi)
            for (int ni = 0; ni < 4; ++ni)
                acc[mi][ni] = __builtin_amdgcn_mfma_f32_16x16x32_bf16(
                    af[mi], bfr[ni], acc[mi][ni], 0, 0, 0);
    }

    for (int ni = 0; ni < 4; ++ni) {
        int col = colBase + wn * 64 + ni * 16 + l16;
        float bv = bias ? bias[col] : 0.0f;
        for (int mi = 0; mi < 4; ++mi) {
            int row0 = rowBase + wm * 64 + mi * 16 + quad * 4;
            for (int r = 0; r < 4; ++r)
                C[(size_t)(row0 + r) * ldc + col] = (TO)(acc[mi][ni][r] + bv);
        }
    }
}

// ---------------- RMSNorm (over full 4096) + RoPE, IN PLACE ----------------
__global__ __launch_bounds__(256)
void rmsnorm_rope(bf16* __restrict__ qkv, const float* __restrict__ qw,
                  const float* __restrict__ kw, const int* __restrict__ pos)
{
    const int t   = blockIdx.x;
    const int sel = blockIdx.y;
    bf16* x = qkv + (size_t)t * QKV_N + sel * 4096;
    const float* w = sel ? kw : qw;
    const int tid = threadIdx.x;

    float ss = 0.f;
    {
        int i0 = tid * 16;
        bf16x8 a = *(const bf16x8*)(x + i0);
        bf16x8 b = *(const bf16x8*)(x + i0 + 8);
        for (int j = 0; j < 8; ++j) { float fa = (float)a[j]; ss += fa * fa; }
        for (int j = 0; j < 8; ++j) { float fb = (float)b[j]; ss += fb * fb; }
    }
    for (int off = 1; off < 64; off <<= 1) ss += __shfl_xor(ss, off, 64);
    __shared__ float red[4];
    if ((tid & 63) == 0) red[tid >> 6] = ss;
    __syncthreads();
    float tot = red[0] + red[1] + red[2] + red[3];
    float rstd = rsqrtf(tot * (1.0f / 4096.0f) + 1e-5f);

    float fp = (float)pos[t];
    for (int i = tid; i < 2048; i += 256) {
        int h = i >> 6;
        int d = i & 63;
        int base = h * 128 + d;
        float x1 = (float)x[base]      * rstd * w[base];
        float x2 = (float)x[base + 64] * rstd * w[base + 64];
        float ang = fp * exp2f(-(float)d * 0.31143075889569023f);
        float s, c;
        sincosf(ang, &s, &c);
        x[base]      = (bf16)(x1 * c - x2 * s);
        x[base + 64] = (bf16)(x2 * c + x1 * s);
    }
}

// ---------------- V transpose ----------------------------------------------
__global__ __launch_bounds__(256)
void v_transpose(const bf16* __restrict__ qkv, bf16* __restrict__ vt)
{
    __shared__ bf16 tile[64][65];
    int t0 = blockIdx.x * 64, d0 = blockIdx.y * 64, h = blockIdx.z;
    int x = threadIdx.x & 63, y4 = threadIdx.x >> 6;
    for (int yy = y4; yy < 64; yy += 4)
        tile[yy][x] = qkv[(size_t)(t0 + yy) * QKV_N + V_OFF + h * HD + d0 + x];
    __syncthreads();
    for (int yy = y4; yy < 64; yy += 4)
        vt[(size_t)(h * HD + d0 + yy) * T_SEQ + t0 + x] = tile[x][yy];
}

// ---------------- Flash attention (causal) ---------------------------------
#define SKP 136
#define SVP 72
#define PBP 72

__global__ __launch_bounds__(256, 2)
void flash_attn(bf16* qkv, const bf16* vt)
{
    __shared__ bf16 sK[64 * SKP];
    __shared__ bf16 sV[128 * SVP];
    __shared__ bf16 pbuf[4 * 16 * PBP];

    const int tid  = threadIdx.x;
    const int wave = tid >> 6, lane = tid & 63;
    const int quad = lane >> 4, l16 = lane & 15;
    const int h    = blockIdx.y;
    const int blk  = blockIdx.x;
    const int q0w  = blk * 64 + wave * 16;

    bf16x8 qf[4];
    {
        const bf16* qrow = qkv + (size_t)(q0w + l16) * QKV_N + h * HD;
        for (int c = 0; c < 4; ++c)
            qf[c] = *(const bf16x8*)(qrow + c * 32 + quad * 8);
    }

    f32x4 oacc[8] = {};
    float m2[4], l[4];
    for (int r = 0; r < 4; ++r) { m2[r] = -1e30f; l[r] = 0.f; }

    const float sc = 0.08838834764831845f * 1.4426950408889634f;
    bf16* pb = pbuf + wave * 16 * PBP;
    const int rowa = q0w + quad * 4;
    const int kend = blk * 64;

    for (int kb = 0; kb <= kend; kb += 64) {
        __syncthreads();
        for (int j = 0; j < 4; ++j) {
            int c = tid + j * 256;
            int r = c >> 4, off = (c & 15) * 8;
            bf16x8 v = *(const bf16x8*)(qkv + (size_t)(kb + r) * QKV_N + 4096 + h * HD + off);
            *(bf16x8*)(sK + r * SKP + off) = v;
        }
        for (int j = 0; j < 4; ++j) {
            int c = tid + j * 256;
            int d = c >> 3, off = (c & 7) * 8;
            bf16x8 v = *(const bf16x8*)(vt + (size_t)(h * HD + d) * T_SEQ + kb + off);
            *(bf16x8*)(sV + d * SVP + off) = v;
        }
        __syncthreads();

        const bool diag = (kb == kend);
        const int stmax = diag ? (wave + 1) : 4;

        f32x4 s[4] = {};
        for (int st = 0; st < 4; ++st) {
            if (st >= stmax) break;
            const bf16* kbase = sK + (st * 16 + l16) * SKP + quad * 8;
            for (int c = 0; c < 4; ++c) {
                bf16x8 kf = *(const bf16x8*)(kbase + c * 32);
                s[st] = __builtin_amdgcn_mfma_f32_16x16x32_bf16(qf[c], kf, s[st], 0, 0, 0);
            }
        }
        for (int st = 0; st < 4; ++st) {
            int col = kb + st * 16 + l16;
            for (int r = 0; r < 4; ++r) {
                float v = s[st][r] * sc;
                s[st][r] = (col <= rowa + r) ? v : -1e30f;
            }
        }
        float alpha[4];
        for (int r = 0; r < 4; ++r) {
            float mx = fmaxf(fmaxf(s[0][r], s[1][r]), fmaxf(s[2][r], s[3][r]));
            for (int off = 1; off < 16; off <<= 1)
                mx = fmaxf(mx, __shfl_xor(mx, off, 64));
            float mnew = fmaxf(m2[r], mx);
            alpha[r] = exp2f(m2[r] - mnew);
            float ps = 0.f;
            for (int st = 0; st < 4; ++st) {
                float p = exp2f(s[st][r] - mnew);
                s[st][r] = p;
                ps += p;
            }
            for (int off = 1; off < 16; off <<= 1)
                ps += __shfl_xor(ps, off, 64);
            l[r] = l[r] * alpha[r] + ps;
            m2[r] = mnew;
        }
        for (int c = 0; c < 8; ++c)
            for (int r = 0; r < 4; ++r)
                oacc[c][r] *= alpha[r];
        for (int st = 0; st < 4; ++st)
            for (int r = 0; r < 4; ++r)
                pb[(quad * 4 + r) * PBP + st * 16 + l16] = (bf16)s[st][r];
        __builtin_amdgcn_s_waitcnt(0xC07F);
        for (int ph = 0; ph < 2; ++ph) {
            bf16x8 pf = *(const bf16x8*)(pb + l16 * PBP + ph * 32 + quad * 8);
            for (int c = 0; c < 8; ++c) {
                bf16x8 vf = *(const bf16x8*)(sV + (c * 16 + l16) * SVP + ph * 32 + quad * 8);
                oacc[c] = __builtin_amdgcn_mfma_f32_16x16x32_bf16(pf, vf, oacc[c], 0, 0, 0);
            }
        }
    }

    for (int r = 0; r < 4; ++r) {
        float inv = 1.0f / l[r];
        int t = q0w + quad * 4 + r;
        for (int c = 0; c < 8; ++c)
            qkv[(size_t)t * QKV_N + V_OFF + h * HD + c * 16 + l16] =
                (bf16)(oacc[c][r] * inv);
    }
}

extern "C" void kernel_launch(void* const* d_in, const int* in_sizes, int n_in,
                              void* d_out, int out_size, void* d_ws, size_t ws_size,
                              hipStream_t stream)
{
    const float* hidden   = (const float*)d_in[0];
    const int*   pos      = (const int*)d_in[1];
    const float* w_qkv    = (const float*)d_in[2];
    const float* b_qkv    = (const float*)d_in[3];
    const float* q_norm_w = (const float*)d_in[4];
    const float* k_norm_w = (const float*)d_in[5];
    const float* w_o      = (const float*)d_in[6];
    float* out = (float*)d_out;

    bf16* qkv = (bf16*)d_ws;                         //  50.33 MB
    bf16* vt  = qkv + (size_t)T_SEQ * QKV_N;         //  16.78 MB
    bf16* wqb = vt  + (size_t)4096 * T_SEQ;          // 100.66 MB
    bf16* wob = wqb + (size_t)QKV_N * 4096;          //  33.55 MB
    bf16* hib = wob + (size_t)4096 * 4096;           //  16.78 MB
    const size_t need = ((size_t)T_SEQ * QKV_N + (size_t)4096 * T_SEQ +
                         (size_t)QKV_N * 4096 + (size_t)4096 * 4096 +
                         (size_t)T_SEQ * 4096) * 2;

    if (ws_size >= need) {
        // bf16 conversions (same work every call; graph-safe)
        f32_to_bf16<<<2048, 256, 0, stream>>>(hidden, hib, T_SEQ * 4096 / 8);
        f32_to_bf16<<<8192, 256, 0, stream>>>(w_qkv, wqb, QKV_N * 4096 / 8);
        f32_to_bf16<<<4096, 256, 0, stream>>>(w_o, wob, 4096 * 4096 / 8);

        gemm_bt_glds<bf16><<<8 * 16 * 12, 256, 0, stream>>>(
            hib, 4096, wqb, b_qkv, qkv, QKV_N, 16, 12, 4096);
        rmsnorm_rope<<<dim3(T_SEQ, 2), 256, 0, stream>>>(qkv, q_norm_w, k_norm_w, pos);
        v_transpose<<<dim3(T_SEQ / 64, 2, NH), 256, 0, stream>>>(qkv, vt);
        flash_attn<<<dim3(T_SEQ / 64, NH), 256, 0, stream>>>(qkv, vt);
        gemm_bt_glds<float><<<8 * 16 * 4, 256, 0, stream>>>(
            qkv + V_OFF, QKV_N, wob, nullptr, out, 4096, 16, 4, 4096);
    } else {
        // fallback: round-3 path (67 MB ws)
        gemm_bt_bias<float, float, bf16><<<dim3(T_SEQ / BM, QKV_N / BN), 256, 0, stream>>>(
            hidden, 4096, w_qkv, b_qkv, qkv, QKV_N, T_SEQ, QKV_N, 4096);
        rmsnorm_rope<<<dim3(T_SEQ, 2), 256, 0, stream>>>(qkv, q_norm_w, k_norm_w, pos);
        v_transpose<<<dim3(T_SEQ / 64, 2, NH), 256, 0, stream>>>(qkv, vt);
        flash_attn<<<dim3(T_SEQ / 64, NH), 256, 0, stream>>>(qkv, vt);
        gemm_bt_bias<bf16, float, float><<<dim3(T_SEQ / BM, 4096 / BN), 256, 0, stream>>>(
            qkv + V_OFF, QKV_N, w_o, nullptr, out, 4096, T_SEQ, 4096, 4096);
    }
}

// Round 6
// 846.638 us; speedup vs baseline: 1.5223x; 1.1344x over previous
//
#include <hip/hip_runtime.h>
#include <hip/hip_bf16.h>

#define T_SEQ 2048
#define NH 32
#define HD 128
#define QKV_N 12288
#define V_OFF 8192

typedef __bf16 bf16;
typedef __attribute__((ext_vector_type(4))) __bf16 bf16x4;
typedef __attribute__((ext_vector_type(8))) __bf16 bf16x8;
typedef __attribute__((ext_vector_type(4))) float f32x4;

#define GLDS16(g, l)                                                        \
  __builtin_amdgcn_global_load_lds(                                         \
      (const __attribute__((address_space(1))) void*)(g),                   \
      (__attribute__((address_space(3))) void*)(l), 16, 0, 0)

// 8-element load -> bf16x8, converting if the source is f32
__device__ inline bf16x8 load8(const bf16* p) { return *(const bf16x8*)p; }
__device__ inline bf16x8 load8(const float* p) {
    f32x4 a = *(const f32x4*)p;
    f32x4 b = *(const f32x4*)(p + 4);
    bf16x8 r;
    r[0] = (bf16)a[0]; r[1] = (bf16)a[1]; r[2] = (bf16)a[2]; r[3] = (bf16)a[3];
    r[4] = (bf16)b[0]; r[5] = (bf16)b[1]; r[6] = (bf16)b[2]; r[7] = (bf16)b[3];
    return r;
}

// ---------------- f32 -> bf16 bulk convert ---------------------------------
__global__ __launch_bounds__(256)
void f32_to_bf16(const float* __restrict__ in, bf16* __restrict__ out, int n8)
{
    for (int i = blockIdx.x * 256 + threadIdx.x; i < n8; i += gridDim.x * 256)
        *(bf16x8*)(out + (size_t)i * 8) = load8(in + (size_t)i * 8);
}

#define BM 128
#define BN 128
#define BK 32

// ---------------- fast GEMM: bf16 A,B; GLDS staging; XCD swizzle -----------
template <typename TO>
__global__ __launch_bounds__(256, 2)
void gemm_bt_glds(const bf16* __restrict__ A, int lda,
                  const bf16* __restrict__ B,
                  const float* __restrict__ bias,
                  TO* __restrict__ C, int ldc,
                  int mTiles, int colPerXcd, int K)
{
    __shared__ bf16 sA[BM * BK];
    __shared__ bf16 sB[BN * BK];
    const int tid  = threadIdx.x;
    const int wave = tid >> 6, lane = tid & 63;
    const int quad = lane >> 4, l16 = lane & 15;
    const int wm = wave >> 1, wn = wave & 1;

    int b = blockIdx.x;
    int xcd = b & 7, i = b >> 3;
    const int rowBase = (i % mTiles) * BM;
    const int colBase = (xcd * colPerXcd + i / mTiles) * BN;

    f32x4 acc[4][4] = {};

    for (int k0 = 0; k0 < K; k0 += BK) {
        __syncthreads();
        for (int r = 0; r < 2; ++r) {
            int cb = wave * 128 + r * 64;
            int c  = cb + lane;
            int row = c >> 2, kg = c & 3;
            GLDS16(A + (size_t)(rowBase + row) * lda + k0 + kg * 8, sA + cb * 8);
            GLDS16(B + (size_t)(colBase + row) * K + k0 + kg * 8, sB + cb * 8);
        }
        __syncthreads();

        bf16x8 af[4], bfr[4];
        for (int mi = 0; mi < 4; ++mi)
            af[mi] = *(const bf16x8*)(sA + (wm * 64 + mi * 16 + l16) * BK + quad * 8);
        for (int ni = 0; ni < 4; ++ni)
            bfr[ni] = *(const bf16x8*)(sB + (wn * 64 + ni * 16 + l16) * BK + quad * 8);
        for (int mi = 0; mi < 4; ++mi)
            for (int ni = 0; ni < 4; ++ni)
                acc[mi][ni] = __builtin_amdgcn_mfma_f32_16x16x32_bf16(
                    af[mi], bfr[ni], acc[mi][ni], 0, 0, 0);
    }

    for (int ni = 0; ni < 4; ++ni) {
        int col = colBase + wn * 64 + ni * 16 + l16;
        float bv = bias ? bias[col] : 0.0f;
        for (int mi = 0; mi < 4; ++mi) {
            int row0 = rowBase + wm * 64 + mi * 16 + quad * 4;
            for (int r = 0; r < 4; ++r)
                C[(size_t)(row0 + r) * ldc + col] = (TO)(acc[mi][ni][r] + bv);
        }
    }
}

// ---------------- fallback GEMM (mixed dtype, register staging) ------------
template <typename TA, typename TB, typename TO>
__global__ __launch_bounds__(256, 2)
void gemm_bt_bias(const TA* __restrict__ A, int lda,
                  const TB* __restrict__ B,
                  const float* __restrict__ bias,
                  TO* __restrict__ C, int ldc,
                  int M, int N, int K)
{
    __shared__ bf16 sA[BM * BK];
    __shared__ bf16 sB[BN * BK];
    const int tid  = threadIdx.x;
    const int wave = tid >> 6, lane = tid & 63;
    const int quad = lane >> 4, l16 = lane & 15;
    const int wm = wave >> 1, wn = wave & 1;
    const int rowBase = blockIdx.x * BM;
    const int colBase = blockIdx.y * BN;

    int c0 = wave * 128 + lane;
    int rowA0 = c0 >> 2, kgA0 = c0 & 3;
    int rowA1 = (c0 + 64) >> 2, kgA1 = (c0 + 64) & 3;

    f32x4 acc[4][4] = {};

    for (int k0 = 0; k0 < K; k0 += BK) {
        bf16x8 ra0 = load8(A + (size_t)(rowBase + rowA0) * lda + k0 + kgA0 * 8);
        bf16x8 ra1 = load8(A + (size_t)(rowBase + rowA1) * lda + k0 + kgA1 * 8);
        bf16x8 rb0 = load8(B + (size_t)(colBase + rowA0) * K + k0 + kgA0 * 8);
        bf16x8 rb1 = load8(B + (size_t)(colBase + rowA1) * K + k0 + kgA1 * 8);
        __syncthreads();
        *(bf16x8*)(sA + rowA0 * BK + kgA0 * 8) = ra0;
        *(bf16x8*)(sA + rowA1 * BK + kgA1 * 8) = ra1;
        *(bf16x8*)(sB + rowA0 * BK + kgA0 * 8) = rb0;
        *(bf16x8*)(sB + rowA1 * BK + kgA1 * 8) = rb1;
        __syncthreads();

        bf16x8 af[4], bfr[4];
        for (int mi = 0; mi < 4; ++mi)
            af[mi] = *(const bf16x8*)(sA + (wm * 64 + mi * 16 + l16) * BK + quad * 8);
        for (int ni = 0; ni < 4; ++ni)
            bfr[ni] = *(const bf16x8*)(sB + (wn * 64 + ni * 16 + l16) * BK + quad * 8);
        for (int mi = 0; mi < 4; ++mi)
            for (int ni = 0; ni < 4; ++ni)
                acc[mi][ni] = __builtin_amdgcn_mfma_f32_16x16x32_bf16(
                    af[mi], bfr[ni], acc[mi][ni], 0, 0, 0);
    }

    for (int ni = 0; ni < 4; ++ni) {
        int col = colBase + wn * 64 + ni * 16 + l16;
        float bv = bias ? bias[col] : 0.0f;
        for (int mi = 0; mi < 4; ++mi) {
            int row0 = rowBase + wm * 64 + mi * 16 + quad * 4;
            for (int r = 0; r < 4; ++r)
                C[(size_t)(row0 + r) * ldc + col] = (TO)(acc[mi][ni][r] + bv);
        }
    }
}

// ---------------- RMSNorm (over full 4096) + RoPE, IN PLACE ----------------
__global__ __launch_bounds__(256)
void rmsnorm_rope(bf16* __restrict__ qkv, const float* __restrict__ qw,
                  const float* __restrict__ kw, const int* __restrict__ pos)
{
    const int t   = blockIdx.x;
    const int sel = blockIdx.y;
    bf16* x = qkv + (size_t)t * QKV_N + sel * 4096;
    const float* w = sel ? kw : qw;
    const int tid = threadIdx.x;

    float ss = 0.f;
    {
        int i0 = tid * 16;
        bf16x8 a = *(const bf16x8*)(x + i0);
        bf16x8 b = *(const bf16x8*)(x + i0 + 8);
        for (int j = 0; j < 8; ++j) { float fa = (float)a[j]; ss += fa * fa; }
        for (int j = 0; j < 8; ++j) { float fb = (float)b[j]; ss += fb * fb; }
    }
    for (int off = 1; off < 64; off <<= 1) ss += __shfl_xor(ss, off, 64);
    __shared__ float red[4];
    if ((tid & 63) == 0) red[tid >> 6] = ss;
    __syncthreads();
    float tot = red[0] + red[1] + red[2] + red[3];
    float rstd = rsqrtf(tot * (1.0f / 4096.0f) + 1e-5f);

    float fp = (float)pos[t];
    for (int i = tid; i < 2048; i += 256) {
        int h = i >> 6;
        int d = i & 63;
        int base = h * 128 + d;
        float x1 = (float)x[base]      * rstd * w[base];
        float x2 = (float)x[base + 64] * rstd * w[base + 64];
        float ang = fp * exp2f(-(float)d * 0.31143075889569023f);
        float s, c;
        sincosf(ang, &s, &c);
        x[base]      = (bf16)(x1 * c - x2 * s);
        x[base + 64] = (bf16)(x2 * c + x1 * s);
    }
}

// ---------------- V transpose ----------------------------------------------
__global__ __launch_bounds__(256)
void v_transpose(const bf16* __restrict__ qkv, bf16* __restrict__ vt)
{
    __shared__ bf16 tile[64][65];
    int t0 = blockIdx.x * 64, d0 = blockIdx.y * 64, h = blockIdx.z;
    int x = threadIdx.x & 63, y4 = threadIdx.x >> 6;
    for (int yy = y4; yy < 64; yy += 4)
        tile[yy][x] = qkv[(size_t)(t0 + yy) * QKV_N + V_OFF + h * HD + d0 + x];
    __syncthreads();
    for (int yy = y4; yy < 64; yy += 4)
        vt[(size_t)(h * HD + d0 + yy) * T_SEQ + t0 + x] = tile[x][yy];
}

// ---------------- Flash attention (causal) ---------------------------------
// Block handles q-tiles {p, 31-p} sequentially (33 K-iterations total each).
// QK computed as S^T = K*Q^T so the softmax k-reduction is in-lane + 2 shfl.
#define SKP 136
#define SVP 72
#define PBP 72

__global__ __launch_bounds__(256, 2)
void flash_attn(bf16* qkv, const bf16* vt)
{
    __shared__ bf16 sK[64 * SKP];
    __shared__ bf16 sV[128 * SVP];
    __shared__ bf16 pbuf[4 * 16 * PBP];

    const int tid  = threadIdx.x;
    const int wave = tid >> 6, lane = tid & 63;
    const int quad = lane >> 4, l16 = lane & 15;
    const int h    = blockIdx.y;

    const float sc = 0.08838834764831845f * 1.4426950408889634f;  // scale*log2e
    bf16* pb = pbuf + wave * 16 * PBP;

    for (int half = 0; half < 2; ++half) {
        const int blk  = half ? (31 - (int)blockIdx.x) : (int)blockIdx.x;
        const int q0w  = blk * 64 + wave * 16;
        const int kend = blk * 64;
        const int qln  = q0w + l16;   // this lane's q row (S^T col)

        bf16x8 qf[4];
        {
            const bf16* qrow = qkv + (size_t)qln * QKV_N + h * HD;
            for (int c = 0; c < 4; ++c)
                qf[c] = *(const bf16x8*)(qrow + c * 32 + quad * 8);
        }

        f32x4 oacc[8] = {};
        float m2 = -1e30f, lsum = 0.f;

        for (int kb = 0; kb <= kend; kb += 64) {
            __syncthreads();
            for (int j = 0; j < 4; ++j) {
                int c = tid + j * 256;
                int r = c >> 4, off = (c & 15) * 8;
                bf16x8 v = *(const bf16x8*)(qkv + (size_t)(kb + r) * QKV_N + 4096 + h * HD + off);
                *(bf16x8*)(sK + r * SKP + off) = v;
            }
            for (int j = 0; j < 4; ++j) {
                int c = tid + j * 256;
                int d = c >> 3, off = (c & 7) * 8;
                bf16x8 v = *(const bf16x8*)(vt + (size_t)(h * HD + d) * T_SEQ + kb + off);
                *(bf16x8*)(sV + d * SVP + off) = v;
            }
            __syncthreads();

            const int stmax = (kb == kend) ? (wave + 1) : 4;

            // S^T tiles: rows = k (quad*4+r), cols = q (l16)
            f32x4 s[4] = {};
            for (int st = 0; st < 4; ++st) {
                if (st >= stmax) break;
                const bf16* kbase = sK + (st * 16 + l16) * SKP + quad * 8;
                for (int c = 0; c < 4; ++c) {
                    bf16x8 kf = *(const bf16x8*)(kbase + c * 32);
                    s[st] = __builtin_amdgcn_mfma_f32_16x16x32_bf16(kf, qf[c], s[st], 0, 0, 0);
                }
            }
            // scale + causal mask: keep if k <= q
            for (int st = 0; st < 4; ++st) {
                int k0r = kb + st * 16 + quad * 4;
                for (int r = 0; r < 4; ++r) {
                    float v = s[st][r] * sc;
                    s[st][r] = (k0r + r <= qln) ? v : -1e30f;
                }
            }
            // online softmax over k (in-lane 16 + 2 shuffles)
            float mx = -1e30f;
            for (int st = 0; st < 4; ++st)
                for (int r = 0; r < 4; ++r) mx = fmaxf(mx, s[st][r]);
            mx = fmaxf(mx, __shfl_xor(mx, 16, 64));
            mx = fmaxf(mx, __shfl_xor(mx, 32, 64));
            float mnew  = fmaxf(m2, mx);
            float alpha = exp2f(m2 - mnew);
            float ps = 0.f;
            for (int st = 0; st < 4; ++st)
                for (int r = 0; r < 4; ++r) {
                    float p = exp2f(s[st][r] - mnew);
                    s[st][r] = p;
                    ps += p;
                }
            ps += __shfl_xor(ps, 16, 64);
            ps += __shfl_xor(ps, 32, 64);
            lsum = lsum * alpha + ps;
            m2 = mnew;

            // redistribute alpha to O's row layout (row q = quad*4+r)
            float ar[4];
            for (int r = 0; r < 4; ++r) ar[r] = __shfl(alpha, quad * 4 + r, 64);
            for (int c = 0; c < 8; ++c)
                for (int r = 0; r < 4; ++r) oacc[c][r] *= ar[r];

            // P store: row q = l16, cols k = st*16 + quad*4 + r (4x b64)
            for (int st = 0; st < 4; ++st) {
                bf16x4 pw;
                for (int r = 0; r < 4; ++r) pw[r] = (bf16)s[st][r];
                *(bf16x4*)(pb + l16 * PBP + st * 16 + quad * 4) = pw;
            }
            __builtin_amdgcn_s_waitcnt(0xC07F);  // lgkmcnt(0)
            for (int ph = 0; ph < 2; ++ph) {
                bf16x8 pf = *(const bf16x8*)(pb + l16 * PBP + ph * 32 + quad * 8);
                for (int c = 0; c < 8; ++c) {
                    bf16x8 vf = *(const bf16x8*)(sV + (c * 16 + l16) * SVP + ph * 32 + quad * 8);
                    oacc[c] = __builtin_amdgcn_mfma_f32_16x16x32_bf16(pf, vf, oacc[c], 0, 0, 0);
                }
            }
        }

        float lr[4];
        for (int r = 0; r < 4; ++r) lr[r] = __shfl(lsum, quad * 4 + r, 64);
        for (int r = 0; r < 4; ++r) {
            float inv = 1.0f / lr[r];
            int t = q0w + quad * 4 + r;
            for (int c = 0; c < 8; ++c)
                qkv[(size_t)t * QKV_N + V_OFF + h * HD + c * 16 + l16] =
                    (bf16)(oacc[c][r] * inv);
        }
    }
}

extern "C" void kernel_launch(void* const* d_in, const int* in_sizes, int n_in,
                              void* d_out, int out_size, void* d_ws, size_t ws_size,
                              hipStream_t stream)
{
    const float* hidden   = (const float*)d_in[0];
    const int*   pos      = (const int*)d_in[1];
    const float* w_qkv    = (const float*)d_in[2];
    const float* b_qkv    = (const float*)d_in[3];
    const float* q_norm_w = (const float*)d_in[4];
    const float* k_norm_w = (const float*)d_in[5];
    const float* w_o      = (const float*)d_in[6];
    float* out = (float*)d_out;

    bf16* qkv = (bf16*)d_ws;                         //  50.33 MB
    bf16* vt  = qkv + (size_t)T_SEQ * QKV_N;         //  16.78 MB
    bf16* wqb = vt  + (size_t)4096 * T_SEQ;          // 100.66 MB
    bf16* wob = wqb + (size_t)QKV_N * 4096;          //  33.55 MB
    bf16* hib = wob + (size_t)4096 * 4096;           //  16.78 MB
    const size_t need = ((size_t)T_SEQ * QKV_N + (size_t)4096 * T_SEQ +
                         (size_t)QKV_N * 4096 + (size_t)4096 * 4096 +
                         (size_t)T_SEQ * 4096) * 2;

    if (ws_size >= need) {
        f32_to_bf16<<<2048, 256, 0, stream>>>(hidden, hib, T_SEQ * 4096 / 8);
        f32_to_bf16<<<8192, 256, 0, stream>>>(w_qkv, wqb, QKV_N * 4096 / 8);
        f32_to_bf16<<<4096, 256, 0, stream>>>(w_o, wob, 4096 * 4096 / 8);

        gemm_bt_glds<bf16><<<8 * 16 * 12, 256, 0, stream>>>(
            hib, 4096, wqb, b_qkv, qkv, QKV_N, 16, 12, 4096);
        rmsnorm_rope<<<dim3(T_SEQ, 2), 256, 0, stream>>>(qkv, q_norm_w, k_norm_w, pos);
        v_transpose<<<dim3(T_SEQ / 64, 2, NH), 256, 0, stream>>>(qkv, vt);
        flash_attn<<<dim3(T_SEQ / 128, NH), 256, 0, stream>>>(qkv, vt);
        gemm_bt_glds<float><<<8 * 16 * 4, 256, 0, stream>>>(
            qkv + V_OFF, QKV_N, wob, nullptr, out, 4096, 16, 4, 4096);
    } else {
        gemm_bt_bias<float, float, bf16><<<dim3(T_SEQ / BM, QKV_N / BN), 256, 0, stream>>>(
            hidden, 4096, w_qkv, b_qkv, qkv, QKV_N, T_SEQ, QKV_N, 4096);
        rmsnorm_rope<<<dim3(T_SEQ, 2), 256, 0, stream>>>(qkv, q_norm_w, k_norm_w, pos);
        v_transpose<<<dim3(T_SEQ / 64, 2, NH), 256, 0, stream>>>(qkv, vt);
        flash_attn<<<dim3(T_SEQ / 128, NH), 256, 0, stream>>>(qkv, vt);
        gemm_bt_bias<bf16, float, float><<<dim3(T_SEQ / BM, 4096 / BN), 256, 0, stream>>>(
            qkv + V_OFF, QKV_N, w_o, nullptr, out, 4096, T_SEQ, 4096, 4096);
    }
}